// Round 8
// baseline (140.666 us; speedup 1.0000x reference)
//
#include <hip/hip_runtime.h>
#include <math.h>

// Problem constants (fixed by setup_inputs)
#define BB    8
#define DD    64
#define NPIX  32768
#define KK    19
#define PP    5
#define NROW  112   // 7 MFMA tiles x 16 rows (group-aligned 4+1 component split)

// LDS (dwords), total 17920 dw = 71680 B -> 2 blocks/CU
//   [0,     7168)  C table: 112 rows x 64 dw (source-swizzled, linear dest)
//   [7168,  7280)  cst: 112 dw
//   [7296, 15488)  X slabs: 4 waves x 64 rows x 32 dw (XOR-swizzled)
//   [15488,17920)  out slabs: 4 waves x 19 rows x 32 dw
#define CSTL  7168
#define XB    7296
#define OBASE 15488

typedef _Float16 half8  __attribute__((ext_vector_type(8)));
typedef __fp16   half2t __attribute__((ext_vector_type(2)));   // cvt_pkrtz return type
typedef float    f32x4  __attribute__((ext_vector_type(4)));

union H8 { half8 v; half2t p[4]; };

// global -> LDS direct copy, 16B/lane. PROLOGUE-ONLY (straight-line code).
__device__ __forceinline__ void gload16(const void* g, void* l) {
    __builtin_amdgcn_global_load_lds(
        (const __attribute__((address_space(1))) void*)g,
        (__attribute__((address_space(3))) void*)l, 16, 0, 0);
}

// Barrier with scheduling fences on both sides: session evidence (R6/R7 fail
// vs R3/R4/R5 pass) indicates hipcc can move LDS ops across s_barrier when a
// loop backedge exists; we fully unroll AND fence to exclude any motion.
__device__ __forceinline__ void barrier_fenced() {
    __builtin_amdgcn_sched_barrier(0);
    __syncthreads();
    __builtin_amdgcn_sched_barrier(0);
}

// ---------------------------------------------------------------------------
// Prep: C table laid out so per-group max needs NO transpose (see R->g,p map).
//  C[R][2d] = mn*i2, C[R][2d+1] = -0.5*i2 ; cst[R] = -0.5*c1 - c2
//  (0.5*D*log(2pi) dropped: LN over k is shift-invariant — exact.)
//  scal = {sum(w^2), sum(w*b), sum(b^2)}.
// ---------------------------------------------------------------------------
__global__ __launch_bounds__(64) void gmm_prep(
        const float* __restrict__ means, const float* __restrict__ diag,
        const float* __restrict__ feat_w, const float* __restrict__ feat_b,
        _Float16* __restrict__ Ch, float* __restrict__ cst,
        float* __restrict__ scal) {
    const int R = blockIdx.x;
    const int d = threadIdx.x;
    if (R == NROW) {
        float w = feat_w[d], b = feat_b[d];
        float s0 = w * w, s1 = w * b, s2 = b * b;
        #pragma unroll
        for (int off = 32; off; off >>= 1) {
            s0 += __shfl_xor(s0, off);
            s1 += __shfl_xor(s1, off);
            s2 += __shfl_xor(s2, off);
        }
        if (d == 0) { scal[0] = s0; scal[1] = s1; scal[2] = s2; }
        return;
    }
    int g, p; bool valid;
    if (R < 80)      { g = 4 * (R >> 4) + ((R >> 2) & 3); p = R & 3; valid = (g < KK); }
    else if (R < 96) { g = 4 * ((R - 80) & 3) + ((R - 80) >> 2); p = 4; valid = true; }
    else             { g = 16 + ((R - 96) >> 2); p = 4; valid = ((R & 3) == 0) && (g < KK); }
    if (valid) {
        const int j = 5 * g + p;
        float mu = means[j * DD + d];
        float sc = diag[j * DD + d];
        float ss = mu * mu;
        #pragma unroll
        for (int off = 32; off; off >>= 1) ss += __shfl_xor(ss, off);
        float inv = 1.f / fmaxf(sqrtf(ss), 1e-12f);
        float mn = mu * inv;
        float i2 = 1.f / (sc * sc);
        Ch[R * 128 + 2 * d]     = (_Float16)(mn * i2);
        Ch[R * 128 + 2 * d + 1] = (_Float16)(-0.5f * i2);
        float c1 = mn * mn * i2;
        float c2 = logf(sc);
        #pragma unroll
        for (int off = 32; off; off >>= 1) {
            c1 += __shfl_xor(c1, off);
            c2 += __shfl_xor(c2, off);
        }
        if (d == 0) cst[R] = -0.5f * c1 - c2;
    } else {
        Ch[R * 128 + 2 * d]     = (_Float16)0.f;
        Ch[R * 128 + 2 * d + 1] = (_Float16)0.f;
        if (d == 0) cst[R] = 0.f;
    }
}

// ---------------------------------------------------------------------------
// Main: 512 blocks x 512 px (4 chunks of 128), chunk loop FULLY UNROLLED to
// straight-line IR (the only pattern that has passed; R6/R7's identical body
// inside a backedge-carrying loop failed — loop pipelining suspected). C table
// staged once (prologue gload16). Per chunk, next chunk's X prefetched to
// REGISTERS at chunk top (latency hidden under moments+MFMA), written to the
// wave-private X slab via plain swizzled ds_write between fenced barriers.
// (256,2): 256-VGPR budget, no spill (R3 lesson).
// ---------------------------------------------------------------------------
__global__ __launch_bounds__(256, 2) void gmm_main(
        const float* __restrict__ bf,
        const float* __restrict__ feat_w, const float* __restrict__ feat_b,
        const float* __restrict__ mask_w, const float* __restrict__ mask_b,
        const _Float16* __restrict__ Ch, const float* __restrict__ cst,
        const float* __restrict__ scal, float* __restrict__ out) {
    __shared__ __align__(16) float smem[17920];   // 71680 B

    const int tid  = threadIdx.x;
    const int w    = tid >> 6;
    const int lane = tid & 63;
    const int m15  = lane & 15;
    const int q    = lane >> 4;
    const int bidx = blockIdx.x;
    const int b    = bidx >> 6;                 // 64 blocks per image
    const int nb   = (bidx & 63) << 9;          // block's 512-px window
    float* xp = smem + XB + w * 2048;           // wave-private X slab
    float* op = smem + OBASE + w * 608;         // wave-private out slab

    const int rr  = lane >> 3;                  // row within 8-row group
    const int c4  = (lane & 7) * 4;             // pixel chunk (4 px)
    const int c4s = c4 ^ (rr << 2);             // swizzled column
    const float* xim = bf + (size_t)b * (DD * NPIX);

    // ---- prologue (straight-line): X chunk 0 + C table + cst in flight ----
    {
        const float* xg0 = xim + nb + (w << 5);
        #pragma unroll
        for (int j = 0; j < 8; ++j)
            gload16(xg0 + (size_t)(8 * j + rr) * NPIX + c4s, xp + 8 * j * 32);
        const char* Cg = (const char*)Ch;
        #pragma unroll
        for (int i = 0; i < 7; ++i) {
            const int f   = (w * 7 + i) * 64 + lane;
            const int row = f >> 4, ch = f & 15;
            gload16(Cg + (size_t)row * 256 + ((ch ^ (row & 15)) * 16),
                    smem + (size_t)(w * 7 + i) * 256);
        }
        if (tid < NROW) smem[CSTL + tid] = cst[tid];
    }

    // loop-invariant: w/b vectors, scal
    float4 wv[4], bv[4];
    #pragma unroll
    for (int ks = 0; ks < 4; ++ks) {
        wv[ks] = *(const float4*)(feat_w + ks * 16 + q * 4);
        bv[ks] = *(const float4*)(feat_b + ks * 16 + q * 4);
    }
    const float W2 = scal[0], WB = scal[1], B2 = scal[2];
    const bool v4 = (q < 3);                    // slot 4 = k 16+q (<19)

    barrier_fenced();   // (0) RAW: X0 + C + cst (vmcnt drained at barrier)

    #pragma unroll
    for (int c = 0; c < 4; ++c) {
        // ---- prefetch next chunk's X to REGISTERS (longest latency first) ----
        float4 xv[8];
        if (c < 3) {
            const float* xg1 = xim + nb + ((c + 1) << 7) + (w << 5);
            #pragma unroll
            for (int j = 0; j < 8; ++j)
                xv[j] = *(const float4*)(xg1 + (size_t)(8 * j + rr) * NPIX + c4);
        }

        // ---- fragment reads: x[row][m] at LDS[row][m ^ ((row&7)<<2)] ----
        float xs0[16], xs1[16];
        #pragma unroll
        for (int ks = 0; ks < 4; ++ks)
            #pragma unroll
            for (int i = 0; i < 4; ++i) {
                const int row = 16 * ks + 4 * q + i;
                const int sw  = (row & 7) << 2;
                xs0[ks * 4 + i] = xp[row * 32 + (m15 ^ sw)];
                xs1[ks * 4 + i] = xp[row * 32 + ((m15 + 16) ^ sw)];
            }

        // ---- moments for both pixels; combine the 4 q-lanes per px ----
        float S1a = 0.f, S2a = 0.f, S3a = 0.f, S4a = 0.f, S5a = 0.f;
        float S1b = 0.f, S2b = 0.f, S3b = 0.f, S4b = 0.f, S5b = 0.f;
        #pragma unroll
        for (int ks = 0; ks < 4; ++ks)
            #pragma unroll
            for (int i = 0; i < 4; ++i) {
                float wd = ((const float*)&wv[ks])[i];
                float bd = ((const float*)&bv[ks])[i];
                float xa = xs0[ks * 4 + i], xb = xs1[ks * 4 + i];
                float ta = wd * xa, tb = wd * xb;
                S1a += xa; S2a = fmaf(xa, xa, S2a); S3a = fmaf(ta, ta, S3a);
                S4a = fmaf(ta, wd, S4a); S5a = fmaf(ta, bd, S5a);
                S1b += xb; S2b = fmaf(xb, xb, S2b); S3b = fmaf(tb, tb, S3b);
                S4b = fmaf(tb, wd, S4b); S5b = fmaf(tb, bd, S5b);
            }
        S1a += __shfl_xor(S1a, 16); S1a += __shfl_xor(S1a, 32);
        S2a += __shfl_xor(S2a, 16); S2a += __shfl_xor(S2a, 32);
        S3a += __shfl_xor(S3a, 16); S3a += __shfl_xor(S3a, 32);
        S4a += __shfl_xor(S4a, 16); S4a += __shfl_xor(S4a, 32);
        S5a += __shfl_xor(S5a, 16); S5a += __shfl_xor(S5a, 32);
        S1b += __shfl_xor(S1b, 16); S1b += __shfl_xor(S1b, 32);
        S2b += __shfl_xor(S2b, 16); S2b += __shfl_xor(S2b, 32);
        S3b += __shfl_xor(S3b, 16); S3b += __shfl_xor(S3b, 32);
        S4b += __shfl_xor(S4b, 16); S4b += __shfl_xor(S4b, 32);
        S5b += __shfl_xor(S5b, 16); S5b += __shfl_xor(S5b, 32);

        float al0, e0, f0, al1, e1, f1;
        {
            float mu  = S1a * (1.f / 64.f);
            float var = fmaxf(S2a * (1.f / 64.f) - mu * mu, 0.f);
            float r   = rsqrtf(var + 1e-5f);
            float Sy2 = r * r * (S3a - 2.f * mu * S4a + mu * mu * W2)
                      + 2.f * r * (S5a - mu * WB) + B2;
            float invn = 1.f / fmaxf(sqrtf(fmaxf(Sy2, 0.f)), 1e-12f);
            al0 = invn * r; e0 = invn; f0 = -al0 * mu;
        }
        {
            float mu  = S1b * (1.f / 64.f);
            float var = fmaxf(S2b * (1.f / 64.f) - mu * mu, 0.f);
            float r   = rsqrtf(var + 1e-5f);
            float Sy2 = r * r * (S3b - 2.f * mu * S4b + mu * mu * W2)
                      + 2.f * r * (S5b - mu * WB) + B2;
            float invn = 1.f / fmaxf(sqrtf(fmaxf(Sy2, 0.f)), 1e-12f);
            al1 = invn * r; e1 = invn; f1 = -al1 * mu;
        }

        // ---- build split-fp16 u B-fragments in registers (packed cvt) ----
        H8 Uh[2][4], Ul[2][4];
        #pragma unroll
        for (int ks = 0; ks < 4; ++ks) {
            #pragma unroll
            for (int i = 0; i < 4; ++i) {
                float wd = ((const float*)&wv[ks])[i];
                float bd = ((const float*)&bv[ks])[i];
                float c0 = fmaf(f0, wd, e0 * bd);
                float c1 = fmaf(f1, wd, e1 * bd);
                float u0 = fmaf(al0, wd * xs0[ks * 4 + i], c0);
                float u1 = fmaf(al1, wd * xs1[ks * 4 + i], c1);
                float q0 = u0 * u0, q1 = u1 * u1;
                half2t h0 = __builtin_amdgcn_cvt_pkrtz(u0, q0);   // [u, usq] hi
                half2t h1 = __builtin_amdgcn_cvt_pkrtz(u1, q1);
                half2t l0 = __builtin_amdgcn_cvt_pkrtz(u0 - (float)h0[0], q0 - (float)h0[1]);
                half2t l1 = __builtin_amdgcn_cvt_pkrtz(u1 - (float)h1[0], q1 - (float)h1[1]);
                Uh[0][ks].p[i] = h0; Ul[0][ks].p[i] = l0;
                Uh[1][ks].p[i] = h1; Ul[1][ks].p[i] = l1;
            }
        }

        barrier_fenced();   // (A) all waves' X reads + prev out-slab reads done

        // ---- write prefetched X into slab: plain swizzled ds_write (global
        //      latency already hidden under moments/Uh-Ul above) ----
        if (c < 3) {
            #pragma unroll
            for (int j = 0; j < 8; ++j)
                *(float4*)(xp + (8 * j + rr) * 32 + c4s) = xv[j];
        }

        // ---- 7 tiles x 16 MFMAs; A row R=16t+m15 at chunk ((ks*4+q)^m15);
        //      per-group max entirely in registers ----
        float m0[5], m1[5];
        #pragma unroll
        for (int t = 0; t < 7; ++t) {
            half8 Ac[4];
            #pragma unroll
            for (int ks = 0; ks < 4; ++ks)
                Ac[ks] = *(const half8*)((const char*)smem
                            + (size_t)(16 * t + m15) * 256 + (((ks * 4 + q) ^ m15) * 16));
            const float4 cv = *(const float4*)(smem + CSTL + 16 * t + 4 * q);
            f32x4 a0 = {0.f, 0.f, 0.f, 0.f}, a1 = {0.f, 0.f, 0.f, 0.f};
            #pragma unroll
            for (int ks = 0; ks < 4; ++ks) {
                a0 = __builtin_amdgcn_mfma_f32_16x16x32_f16(Ac[ks], Uh[0][ks].v, a0, 0, 0, 0);
                a1 = __builtin_amdgcn_mfma_f32_16x16x32_f16(Ac[ks], Uh[1][ks].v, a1, 0, 0, 0);
            }
            #pragma unroll
            for (int ks = 0; ks < 4; ++ks) {
                a0 = __builtin_amdgcn_mfma_f32_16x16x32_f16(Ac[ks], Ul[0][ks].v, a0, 0, 0, 0);
                a1 = __builtin_amdgcn_mfma_f32_16x16x32_f16(Ac[ks], Ul[1][ks].v, a1, 0, 0, 0);
            }
            if (t < 5) {
                m0[t] = fmaxf(fmaxf(a0[0] + cv.x, a0[1] + cv.y), fmaxf(a0[2] + cv.z, a0[3] + cv.w));
                m1[t] = fmaxf(fmaxf(a1[0] + cv.x, a1[1] + cv.y), fmaxf(a1[2] + cv.z, a1[3] + cv.w));
            } else if (t == 5) {
                m0[0] = fmaxf(m0[0], a0[0] + cv.x);
                m0[1] = fmaxf(m0[1], a0[1] + cv.y);
                m0[2] = fmaxf(m0[2], a0[2] + cv.z);
                m0[3] = fmaxf(m0[3], a0[3] + cv.w);
                m1[0] = fmaxf(m1[0], a1[0] + cv.x);
                m1[1] = fmaxf(m1[1], a1[1] + cv.y);
                m1[2] = fmaxf(m1[2], a1[2] + cv.z);
                m1[3] = fmaxf(m1[3], a1[3] + cv.w);
            } else {
                m0[4] = fmaxf(m0[4], a0[0] + cv.x);
                m1[4] = fmaxf(m1[4], a1[0] + cv.x);
            }
        }

        // ---- mask LayerNorm over 19 k's: 8 shfl_xor ----
        float S0 = m0[0] + m0[1] + m0[2] + m0[3] + (v4 ? m0[4] : 0.f);
        float S1 = m1[0] + m1[1] + m1[2] + m1[3] + (v4 ? m1[4] : 0.f);
        S0 += __shfl_xor(S0, 16); S0 += __shfl_xor(S0, 32);
        S1 += __shfl_xor(S1, 16); S1 += __shfl_xor(S1, 32);
        const float mu0 = S0 * (1.f / 19.f), mu1 = S1 * (1.f / 19.f);
        float V0, V1;
        {
            float d0 = m0[0] - mu0, d1 = m0[1] - mu0, d2 = m0[2] - mu0;
            float d3 = m0[3] - mu0, d4 = m0[4] - mu0;
            V0 = d0 * d0 + d1 * d1 + d2 * d2 + d3 * d3 + (v4 ? d4 * d4 : 0.f);
        }
        {
            float d0 = m1[0] - mu1, d1 = m1[1] - mu1, d2 = m1[2] - mu1;
            float d3 = m1[3] - mu1, d4 = m1[4] - mu1;
            V1 = d0 * d0 + d1 * d1 + d2 * d2 + d3 * d3 + (v4 ? d4 * d4 : 0.f);
        }
        V0 += __shfl_xor(V0, 16); V0 += __shfl_xor(V0, 32);
        V1 += __shfl_xor(V1, 16); V1 += __shfl_xor(V1, 32);
        const float r0 = rsqrtf(V0 * (1.f / 19.f) + 1e-5f);
        const float r1 = rsqrtf(V1 * (1.f / 19.f) + 1e-5f);

        // ---- output transpose into wave out-slab rows 0..18 ----
        #pragma unroll
        for (int t = 0; t < 5; ++t) {
            const int k = 4 * t + q;
            if (t < 4 || v4) {
                const float mw = mask_w[k], mb = mask_b[k];
                op[k * 32 + m15]      = (m0[t] - mu0) * r0 * mw + mb;
                op[k * 32 + 16 + m15] = (m1[t] - mu1) * r1 * mw + mb;
            }
        }

        barrier_fenced();   // (B) X-slab writes + out-slab writes drained

        // ---- f4 full-line stores from out slab ----
        float* ob = out + (size_t)b * (KK * NPIX) + nb + (c << 7) + (w << 5);
        #pragma unroll
        for (int rnd = 0; rnd < 3; ++rnd) {
            const int idx = rnd * 64 + lane;
            if (idx < 152) {
                const int k = idx >> 3, cc = (idx & 7) * 4;
                float4 v = *(const float4*)(op + k * 32 + cc);
                *(float4*)(ob + (size_t)k * NPIX + cc) = v;
            }
        }
    }
}

extern "C" void kernel_launch(void* const* d_in, const int* in_sizes, int n_in,
                              void* d_out, int out_size, void* d_ws, size_t ws_size,
                              hipStream_t stream) {
    const float* base_feature = (const float*)d_in[0]; // [8, 64, 32768]
    const float* means        = (const float*)d_in[1]; // [19, 5, 64]
    const float* diagonal     = (const float*)d_in[2]; // [19, 5, 64]
    const float* feat_w       = (const float*)d_in[3]; // [64]
    const float* feat_b       = (const float*)d_in[4]; // [64]
    const float* mask_w       = (const float*)d_in[5]; // [19]
    const float* mask_b       = (const float*)d_in[6]; // [19]
    float* out = (float*)d_out;                        // [8, 19, 32768] fp32

    // ws layout: Ch[112*128] f16 | cst[112] f32 | scal[3] f32
    _Float16* Ch = (_Float16*)d_ws;
    float* cst   = (float*)(Ch + NROW * 128);
    float* scal  = cst + NROW;

    gmm_prep<<<NROW + 1, 64, 0, stream>>>(means, diagonal, feat_w, feat_b, Ch, cst, scal);

    gmm_main<<<(BB * NPIX) / 512, 256, 0, stream>>>(
        base_feature, feat_w, feat_b, mask_w, mask_b, Ch, cst, scal, out);
}

// Round 11
// 121.863 us; speedup vs baseline: 1.1543x; 1.1543x over previous
//
#include <hip/hip_runtime.h>
#include <math.h>

// Problem constants (fixed by setup_inputs)
#define BB    8
#define DD    64
#define NPIX  32768
#define KK    19
#define PP    5
#define NROW  112   // 7 MFMA tiles x 16 rows (group-aligned 4+1 component split)

// LDS (dwords), total 8304 dw = 33216 B -> 4 blocks/CU by LDS
//   [0, 8192)    X slab: 4 waves x 64 rows x 32 dw (swizzled via global source).
//                OVERLAID after X reads by the C table (112 rows x 64 dw = 7168 dw),
//                then by the per-wave output slab (rows 0..18 x 32 dw).
//   [8192, 8304) cst: 112 dw
#define XDW    2048       // per-wave X slab dwords
#define CSTOFF 8192

typedef _Float16 half8  __attribute__((ext_vector_type(8)));
typedef __fp16   half2t __attribute__((ext_vector_type(2)));   // cvt_pkrtz return type
typedef float    f32x4  __attribute__((ext_vector_type(4)));

union H8 { half8 v; half2t p[4]; };

// global -> LDS direct copy, 16B/lane. LDS dest = wave-uniform base + lane*16
// (HW rule); global src is per-lane. Swizzled layouts are achieved by
// pre-swizzling the SOURCE address while LDS stays linear (guide rule 21).
// SESSION RULE (R6/R7/R9/R10 failures): each LDS region gets AT MOST ONE
// staging generation per kernel, in straight-line code. Never re-stage.
__device__ __forceinline__ void gload16(const void* g, void* l) {
    __builtin_amdgcn_global_load_lds(
        (const __attribute__((address_space(1))) void*)g,
        (__attribute__((address_space(3))) void*)l, 16, 0, 0);
}

// ---------------------------------------------------------------------------
// Prep: C table laid out so per-group max needs NO transpose (see R->g,p map).
//  C[R][2d] = mn*i2, C[R][2d+1] = -0.5*i2 ; cst[R] = -0.5*c1 - c2
//  (0.5*D*log(2pi) dropped: LN over k is shift-invariant — exact.)
//  scal = {sum(w^2), sum(w*b), sum(b^2)}.
// ---------------------------------------------------------------------------
__global__ __launch_bounds__(64) void gmm_prep(
        const float* __restrict__ means, const float* __restrict__ diag,
        const float* __restrict__ feat_w, const float* __restrict__ feat_b,
        _Float16* __restrict__ Ch, float* __restrict__ cst,
        float* __restrict__ scal) {
    const int R = blockIdx.x;
    const int d = threadIdx.x;
    if (R == NROW) {
        float w = feat_w[d], b = feat_b[d];
        float s0 = w * w, s1 = w * b, s2 = b * b;
        #pragma unroll
        for (int off = 32; off; off >>= 1) {
            s0 += __shfl_xor(s0, off);
            s1 += __shfl_xor(s1, off);
            s2 += __shfl_xor(s2, off);
        }
        if (d == 0) { scal[0] = s0; scal[1] = s1; scal[2] = s2; }
        return;
    }
    int g, p; bool valid;
    if (R < 80)      { g = 4 * (R >> 4) + ((R >> 2) & 3); p = R & 3; valid = (g < KK); }
    else if (R < 96) { g = 4 * ((R - 80) & 3) + ((R - 80) >> 2); p = 4; valid = true; }
    else             { g = 16 + ((R - 96) >> 2); p = 4; valid = ((R & 3) == 0) && (g < KK); }
    if (valid) {
        const int j = 5 * g + p;
        float mu = means[j * DD + d];
        float sc = diag[j * DD + d];
        float ss = mu * mu;
        #pragma unroll
        for (int off = 32; off; off >>= 1) ss += __shfl_xor(ss, off);
        float inv = 1.f / fmaxf(sqrtf(ss), 1e-12f);
        float mn = mu * inv;
        float i2 = 1.f / (sc * sc);
        Ch[R * 128 + 2 * d]     = (_Float16)(mn * i2);
        Ch[R * 128 + 2 * d + 1] = (_Float16)(-0.5f * i2);
        float c1 = mn * mn * i2;
        float c2 = logf(sc);
        #pragma unroll
        for (int off = 32; off; off >>= 1) {
            c1 += __shfl_xor(c1, off);
            c2 += __shfl_xor(c2, off);
        }
        if (d == 0) cst[R] = -0.5f * c1 - c2;
    } else {
        Ch[R * 128 + 2 * d]     = (_Float16)0.f;
        Ch[R * 128 + 2 * d + 1] = (_Float16)0.f;
        if (d == 0) cst[R] = 0.f;
    }
}

// ---------------------------------------------------------------------------
// Main: 256 thr = 4 waves, 32 px each. LDS overlay (C table over dead X slab)
// cuts LDS 63.7KB -> 33.2KB (4 blocks/CU). All staging via global_load_lds
// width=16 with pre-swizzled global sources (linear LDS dest): zero staging
// VGPRs, full-line transactions everywhere. (256,3): no-spill VGPR budget.
// VERIFIED at 122.4 us (R5). Re-staging variants (R6/R7/R9/R10) all failed
// correctness — do not re-introduce multi-generation LDS staging.
// ---------------------------------------------------------------------------
__global__ __launch_bounds__(256, 3) void gmm_main(
        const float* __restrict__ bf,
        const float* __restrict__ feat_w, const float* __restrict__ feat_b,
        const float* __restrict__ mask_w, const float* __restrict__ mask_b,
        const _Float16* __restrict__ Ch, const float* __restrict__ cst,
        const float* __restrict__ scal, float* __restrict__ out) {
    __shared__ __align__(16) float smem[8304];   // 33216 B

    const int tid  = threadIdx.x;
    const int w    = tid >> 6;
    const int lane = tid & 63;
    const int m15  = lane & 15;
    const int q    = lane >> 4;
    const int bidx = blockIdx.x;
    const int b    = bidx >> 8;                        // 256 blocks per image
    const int n0   = ((bidx & 255) << 7) + (w << 5);   // wave's 32 pixels
    float* lp = smem + w * XDW;                        // wave-private X slab

    // ---- X stage: 8 x global_load_lds, each = 8 rows x 128B full lines.
    // Lane (rr, c4) fetches global px-chunk (c4 ^ (rr<<2)); linear LDS dest
    // => LDS[row][c] = x[row][c ^ ((row&7)<<2)]  (the swizzled layout). ----
    const int rr  = lane >> 3;                  // row within 8-row group
    const int c4s = ((lane & 7) * 4) ^ (rr << 2);
    const float* xgb = bf + (size_t)b * (DD * NPIX) + n0;
    #pragma unroll
    for (int j = 0; j < 8; ++j)
        gload16(xgb + (size_t)(8 * j + rr) * NPIX + c4s, lp + 8 * j * 32);

    // cst stage (region disjoint from X slab)
    if (tid < NROW) smem[CSTOFF + tid] = cst[tid];

    // ---- w/b vectors ----
    float4 wv[4], bv[4];
    #pragma unroll
    for (int ks = 0; ks < 4; ++ks) {
        wv[ks] = *(const float4*)(feat_w + ks * 16 + q * 4);
        bv[ks] = *(const float4*)(feat_b + ks * 16 + q * 4);
    }
    const float W2 = scal[0], WB = scal[1], B2 = scal[2];

    __syncthreads();   // (1) RAW: X slab (vmcnt drain) + cst

    // ---- fragment reads: x[row][m] at LDS[row][m ^ ((row&7)<<2)] ----
    float xs0[16], xs1[16];
    #pragma unroll
    for (int ks = 0; ks < 4; ++ks)
        #pragma unroll
        for (int i = 0; i < 4; ++i) {
            const int row = 16 * ks + 4 * q + i;
            const int sw  = (row & 7) << 2;
            xs0[ks * 4 + i] = lp[row * 32 + (m15 ^ sw)];
            xs1[ks * 4 + i] = lp[row * 32 + ((m15 + 16) ^ sw)];
        }

    __syncthreads();   // (2) WAR: X slab dead; C table may now overwrite it

    // ---- C stage: 7 x global_load_lds per wave into [0, 7168) dw, linear.
    // Lane at f4-slot f=(row,chunk) fetches global chunk (chunk ^ (row&15))
    // => tile-loop b128 reads are bank-even. Latency overlaps moments below.
    // (One generation into a fresh region: the R5-proven pattern.) ----
    {
        const char* Cg = (const char*)Ch;
        #pragma unroll
        for (int i = 0; i < 7; ++i) {
            const int f   = (w * 7 + i) * 64 + lane;
            const int row = f >> 4, ch = f & 15;
            gload16(Cg + (size_t)row * 256 + ((ch ^ (row & 15)) * 16),
                    smem + (size_t)(w * 7 + i) * 256);
        }
    }

    // ---- moments for both pixels; combine the 4 q-lanes per px ----
    float S1a = 0.f, S2a = 0.f, S3a = 0.f, S4a = 0.f, S5a = 0.f;
    float S1b = 0.f, S2b = 0.f, S3b = 0.f, S4b = 0.f, S5b = 0.f;
    #pragma unroll
    for (int ks = 0; ks < 4; ++ks)
        #pragma unroll
        for (int i = 0; i < 4; ++i) {
            float wd = ((const float*)&wv[ks])[i];
            float bd = ((const float*)&bv[ks])[i];
            float xa = xs0[ks * 4 + i], xb = xs1[ks * 4 + i];
            float ta = wd * xa, tb = wd * xb;
            S1a += xa; S2a = fmaf(xa, xa, S2a); S3a = fmaf(ta, ta, S3a);
            S4a = fmaf(ta, wd, S4a); S5a = fmaf(ta, bd, S5a);
            S1b += xb; S2b = fmaf(xb, xb, S2b); S3b = fmaf(tb, tb, S3b);
            S4b = fmaf(tb, wd, S4b); S5b = fmaf(tb, bd, S5b);
        }
    S1a += __shfl_xor(S1a, 16); S1a += __shfl_xor(S1a, 32);
    S2a += __shfl_xor(S2a, 16); S2a += __shfl_xor(S2a, 32);
    S3a += __shfl_xor(S3a, 16); S3a += __shfl_xor(S3a, 32);
    S4a += __shfl_xor(S4a, 16); S4a += __shfl_xor(S4a, 32);
    S5a += __shfl_xor(S5a, 16); S5a += __shfl_xor(S5a, 32);
    S1b += __shfl_xor(S1b, 16); S1b += __shfl_xor(S1b, 32);
    S2b += __shfl_xor(S2b, 16); S2b += __shfl_xor(S2b, 32);
    S3b += __shfl_xor(S3b, 16); S3b += __shfl_xor(S3b, 32);
    S4b += __shfl_xor(S4b, 16); S4b += __shfl_xor(S4b, 32);
    S5b += __shfl_xor(S5b, 16); S5b += __shfl_xor(S5b, 32);

    float al0, e0, f0, al1, e1, f1;
    {
        float mu  = S1a * (1.f / 64.f);
        float var = fmaxf(S2a * (1.f / 64.f) - mu * mu, 0.f);
        float r   = rsqrtf(var + 1e-5f);
        float Sy2 = r * r * (S3a - 2.f * mu * S4a + mu * mu * W2)
                  + 2.f * r * (S5a - mu * WB) + B2;
        float invn = 1.f / fmaxf(sqrtf(fmaxf(Sy2, 0.f)), 1e-12f);
        al0 = invn * r; e0 = invn; f0 = -al0 * mu;
    }
    {
        float mu  = S1b * (1.f / 64.f);
        float var = fmaxf(S2b * (1.f / 64.f) - mu * mu, 0.f);
        float r   = rsqrtf(var + 1e-5f);
        float Sy2 = r * r * (S3b - 2.f * mu * S4b + mu * mu * W2)
                  + 2.f * r * (S5b - mu * WB) + B2;
        float invn = 1.f / fmaxf(sqrtf(fmaxf(Sy2, 0.f)), 1e-12f);
        al1 = invn * r; e1 = invn; f1 = -al1 * mu;
    }

    // ---- build split-fp16 u B-fragments in registers (packed cvt) ----
    H8 Uh[2][4], Ul[2][4];
    #pragma unroll
    for (int ks = 0; ks < 4; ++ks) {
        #pragma unroll
        for (int i = 0; i < 4; ++i) {
            float wd = ((const float*)&wv[ks])[i];
            float bd = ((const float*)&bv[ks])[i];
            float c0 = fmaf(f0, wd, e0 * bd);
            float c1 = fmaf(f1, wd, e1 * bd);
            float u0 = fmaf(al0, wd * xs0[ks * 4 + i], c0);
            float u1 = fmaf(al1, wd * xs1[ks * 4 + i], c1);
            float q0 = u0 * u0, q1 = u1 * u1;
            half2t h0 = __builtin_amdgcn_cvt_pkrtz(u0, q0);   // [u, usq] hi
            half2t h1 = __builtin_amdgcn_cvt_pkrtz(u1, q1);
            half2t l0 = __builtin_amdgcn_cvt_pkrtz(u0 - (float)h0[0], q0 - (float)h0[1]);
            half2t l1 = __builtin_amdgcn_cvt_pkrtz(u1 - (float)h1[0], q1 - (float)h1[1]);
            Uh[0][ks].p[i] = h0; Ul[0][ks].p[i] = l0;
            Uh[1][ks].p[i] = h1; Ul[1][ks].p[i] = l1;
        }
    }

    __syncthreads();   // (3) RAW: C table ready (vmcnt drain of gload16)

    // ---- 7 tiles x 16 MFMAs; A row R=16t+m15 at chunk ((ks*4+q) ^ m15);
    //      per-group max entirely in registers ----
    float m0[5], m1[5];
    #pragma unroll
    for (int t = 0; t < 7; ++t) {
        half8 Ac[4];
        #pragma unroll
        for (int ks = 0; ks < 4; ++ks)
            Ac[ks] = *(const half8*)((const char*)smem
                        + (size_t)(16 * t + m15) * 256 + (((ks * 4 + q) ^ m15) * 16));
        const float4 cv = *(const float4*)(smem + CSTOFF + 16 * t + 4 * q);
        f32x4 a0 = {0.f, 0.f, 0.f, 0.f}, a1 = {0.f, 0.f, 0.f, 0.f};
        #pragma unroll
        for (int ks = 0; ks < 4; ++ks) {
            a0 = __builtin_amdgcn_mfma_f32_16x16x32_f16(Ac[ks], Uh[0][ks].v, a0, 0, 0, 0);
            a1 = __builtin_amdgcn_mfma_f32_16x16x32_f16(Ac[ks], Uh[1][ks].v, a1, 0, 0, 0);
        }
        #pragma unroll
        for (int ks = 0; ks < 4; ++ks) {
            a0 = __builtin_amdgcn_mfma_f32_16x16x32_f16(Ac[ks], Ul[0][ks].v, a0, 0, 0, 0);
            a1 = __builtin_amdgcn_mfma_f32_16x16x32_f16(Ac[ks], Ul[1][ks].v, a1, 0, 0, 0);
        }
        if (t < 5) {
            m0[t] = fmaxf(fmaxf(a0[0] + cv.x, a0[1] + cv.y), fmaxf(a0[2] + cv.z, a0[3] + cv.w));
            m1[t] = fmaxf(fmaxf(a1[0] + cv.x, a1[1] + cv.y), fmaxf(a1[2] + cv.z, a1[3] + cv.w));
        } else if (t == 5) {
            m0[0] = fmaxf(m0[0], a0[0] + cv.x);
            m0[1] = fmaxf(m0[1], a0[1] + cv.y);
            m0[2] = fmaxf(m0[2], a0[2] + cv.z);
            m0[3] = fmaxf(m0[3], a0[3] + cv.w);
            m1[0] = fmaxf(m1[0], a1[0] + cv.x);
            m1[1] = fmaxf(m1[1], a1[1] + cv.y);
            m1[2] = fmaxf(m1[2], a1[2] + cv.z);
            m1[3] = fmaxf(m1[3], a1[3] + cv.w);
        } else {
            m0[4] = fmaxf(m0[4], a0[0] + cv.x);
            m1[4] = fmaxf(m1[4], a1[0] + cv.x);
        }
    }

    // ---- mask LayerNorm over 19 k's: 8 shfl_xor ----
    const bool v4 = (q < 3);                               // slot 4 = k 16+q (<19)
    float S0 = m0[0] + m0[1] + m0[2] + m0[3] + (v4 ? m0[4] : 0.f);
    float S1 = m1[0] + m1[1] + m1[2] + m1[3] + (v4 ? m1[4] : 0.f);
    S0 += __shfl_xor(S0, 16); S0 += __shfl_xor(S0, 32);
    S1 += __shfl_xor(S1, 16); S1 += __shfl_xor(S1, 32);
    const float mu0 = S0 * (1.f / 19.f), mu1 = S1 * (1.f / 19.f);
    float V0, V1;
    {
        float d0 = m0[0] - mu0, d1 = m0[1] - mu0, d2 = m0[2] - mu0;
        float d3 = m0[3] - mu0, d4 = m0[4] - mu0;
        V0 = d0 * d0 + d1 * d1 + d2 * d2 + d3 * d3 + (v4 ? d4 * d4 : 0.f);
    }
    {
        float d0 = m1[0] - mu1, d1 = m1[1] - mu1, d2 = m1[2] - mu1;
        float d3 = m1[3] - mu1, d4 = m1[4] - mu1;
        V1 = d0 * d0 + d1 * d1 + d2 * d2 + d3 * d3 + (v4 ? d4 * d4 : 0.f);
    }
    V0 += __shfl_xor(V0, 16); V0 += __shfl_xor(V0, 32);
    V1 += __shfl_xor(V1, 16); V1 += __shfl_xor(V1, 32);
    const float r0 = rsqrtf(V0 * (1.f / 19.f) + 1e-5f);
    const float r1 = rsqrtf(V1 * (1.f / 19.f) + 1e-5f);

    __syncthreads();   // (4) WAR: C table dead; output slab may overwrite

    // ---- output transpose into wave slice rows 0..18 ----
    #pragma unroll
    for (int t = 0; t < 5; ++t) {
        const int k = 4 * t + q;
        if (t < 4 || v4) {
            const float mw = mask_w[k], mb = mask_b[k];
            lp[k * 32 + m15]      = (m0[t] - mu0) * r0 * mw + mb;
            lp[k * 32 + 16 + m15] = (m1[t] - mu1) * r1 * mw + mb;
        }
    }

    __syncthreads();   // (5) RAW: out slab

    float* ob = out + (size_t)b * (KK * NPIX) + n0;
    #pragma unroll
    for (int rnd = 0; rnd < 3; ++rnd) {
        const int idx = rnd * 64 + lane;
        if (idx < 152) {
            const int k = idx >> 3, cc = (idx & 7) * 4;
            float4 v = *(const float4*)(lp + k * 32 + cc);
            *(float4*)(ob + (size_t)k * NPIX + cc) = v;
        }
    }
}

extern "C" void kernel_launch(void* const* d_in, const int* in_sizes, int n_in,
                              void* d_out, int out_size, void* d_ws, size_t ws_size,
                              hipStream_t stream) {
    const float* base_feature = (const float*)d_in[0]; // [8, 64, 32768]
    const float* means        = (const float*)d_in[1]; // [19, 5, 64]
    const float* diagonal     = (const float*)d_in[2]; // [19, 5, 64]
    const float* feat_w       = (const float*)d_in[3]; // [64]
    const float* feat_b       = (const float*)d_in[4]; // [64]
    const float* mask_w       = (const float*)d_in[5]; // [19]
    const float* mask_b       = (const float*)d_in[6]; // [19]
    float* out = (float*)d_out;                        // [8, 19, 32768] fp32

    // ws layout: Ch[112*128] f16 | cst[112] f32 | scal[3] f32
    _Float16* Ch = (_Float16*)d_ws;
    float* cst   = (float*)(Ch + NROW * 128);
    float* scal  = cst + NROW;

    gmm_prep<<<NROW + 1, 64, 0, stream>>>(means, diagonal, feat_w, feat_b, Ch, cst, scal);

    gmm_main<<<(BB * NPIX) / 128, 256, 0, stream>>>(
        base_feature, feat_w, feat_b, mask_w, mask_b, Ch, cst, scal, out);
}